// Round 2
// baseline (6131.368 us; speedup 1.0000x reference)
//
#include <hip/hip_runtime.h>
#include <math.h>

// Problem constants
constexpr int B  = 128;
constexpr int T  = 512;
constexpr int IN = 32;
constexpr int H  = 256;
constexpr int D  = 2 * H;     // 512
constexpr int NC = 1024;      // codebook entries

// cooperative GRU geometry
constexpr int NG   = 64;      // groups (32 fwd + 32 bwd)
constexpr int GW   = 4;       // WGs per group
constexpr int SEQ  = 4;       // sequences per group
constexpr int NTHR = 768;     // 8 k-chunks x 96 row-pairs

// ---------------------------------------------------------------------------
// prep kernels
// ---------------------------------------------------------------------------

// zeroes counts, lsum, and the exchange slab (131072 u64 = 1 MB).
// grid 512 x 256 = 131072 threads, one u64 each.
__global__ void k_zero(int* __restrict__ counts, double* __restrict__ lsum,
                       unsigned long long* __restrict__ slab) {
    const int i = blockIdx.x * 256 + threadIdx.x;
    if (i < NC) counts[i] = 0;
    if (i == 0) *lsum = 0.0;
    slab[i] = 0ull;
}

__global__ void k_lengths(const int* __restrict__ mask, int* __restrict__ last) {
    const int b = blockIdx.x;
    const int t = threadIdx.x;   // 64 threads = 1 wave
    int s = 0;
    #pragma unroll
    for (int m = 0; m < T / 64; ++m) s += mask[b * T + m * 64 + t];
    #pragma unroll
    for (int off = 32; off > 0; off >>= 1) s += __shfl_down(s, off, 64);
    if (t == 0) last[b] = s - 1;
}

// build direction-pure, length-sorted groups of 4 tasks
__global__ void k_plan(const int* __restrict__ last, int* __restrict__ plan,
                       int* __restrict__ slen, int* __restrict__ glen) {
    __shared__ int ll[B];
    const int t = threadIdx.x;   // 128
    ll[t] = last[t];
    __syncthreads();
    const int lf = ll[t] + 1;       // fwd steps
    const int lb = T - ll[t];       // bwd steps
    int rf = 0, rb = 0;
    for (int j = 0; j < B; ++j) {
        const int ljf = ll[j] + 1, ljb = T - ll[j];
        rf += (ljf > lf) || (ljf == lf && j < t);   // descending
        rb += (ljb > lb) || (ljb == lb && j < t);
    }
    plan[rf] = t;       slen[rf] = lf;
    plan[128 + rb] = t; slen[128 + rb] = lb;
    if ((rf & 3) == 0) glen[rf >> 2] = lf;          // rank 4g = group max
    if ((rb & 3) == 0) glen[32 + (rb >> 2)] = lb;
}

// transpose codebook for k_vq
__global__ void k_transpose(float* __restrict__ dst, const float* __restrict__ src,
                            int rows, int cols) {
    const int idx = blockIdx.x * 256 + threadIdx.x;
    const int r = idx % rows;
    const int c = idx / rows;
    dst[idx] = src[r * cols + c];
}

__global__ void k_cbn2(const float* __restrict__ cb, double* __restrict__ cbn2) {
    const int c = blockIdx.x * 256 + threadIdx.x;
    double s = 0.0;
    for (int k = 0; k < D; ++k) {
        const double e = (double)cb[c * D + k];
        s += e * e;
    }
    cbn2[c] = s;
}

// ---------------------------------------------------------------------------
// Cooperative GRU with pipelined exchange.
//
// Per step N:
//   - waves 8-10 (tid 512..703): each fetches ONE peer's h[N-1] slice from the
//     agent-scope slab (published in the peers' phase2 of step N-1, so it is
//     usually already LLC-visible), writes it to h4, and bumps an LDS counter.
//   - all 768 threads compute phase-1 partial dots in 4 sub-phases. Each
//     thread's 32 k are remapped as 8 k PER SLICE, ordered slice-relative to
//     our own w (q=0 -> own slice, already in LDS). Sub-phase q>=1 spins on
//     cntL[p] (cheap LDS broadcast read) until slice p has landed -> the LLC
//     round trip overlaps own-slice compute + x-partials instead of being
//     serially exposed after the barrier.
//   - wave 11 prefetches x for step N+1 (pollers keep a clean vmcnt path).
//   - mid barrier; gate waves (tid<256) reduce P/Px, apply activations,
//     write own h4 slice, publish to the step-N slab; end barrier.
//
// Race-freedom (2-barrier chain, same as before): our gather(N) completes
// before our mid-bar(N) -> before our publish(N) -> before any peer can reach
// publish(N+1), which is the earliest same-parity overwrite of slab words
// gather(N) reads. Step-1 gather reads the zeroed slab: tag 0 >= 0 and value
// 0.0f == h0, so no special case.
// ---------------------------------------------------------------------------

__device__ __forceinline__ float sigmoidf_(float x) {
    return 1.0f / (1.0f + expf(-x));
}

#define FMA4(acc, wv, hv)                                                     \
    acc.x = fmaf(wv.x, hv.x, acc.x); acc.y = fmaf(wv.y, hv.y, acc.y);         \
    acc.z = fmaf(wv.z, hv.z, acc.z); acc.w = fmaf(wv.w, hv.w, acc.w);

__global__ __launch_bounds__(NTHR, 3) void k_gru(
    const float* __restrict__ traj,
    const float* __restrict__ Whf, const float* __restrict__ Whb,
    const float* __restrict__ Wxf, const float* __restrict__ Wxb,
    const float* __restrict__ bxf, const float* __restrict__ bhf,
    const float* __restrict__ bxb, const float* __restrict__ bhb,
    const int* __restrict__ plan, const int* __restrict__ slen,
    const int* __restrict__ glen,
    unsigned long long* __restrict__ hgt,   // [2][NG][GW][SEQ*64] agent scope
    float* __restrict__ ze)                 // [B][512]
{
    const int g   = blockIdx.x & 63;     // same-XCD members under %8 round-robin
    const int w   = blockIdx.x >> 6;
    const int dir = (g >= 32) ? 1 : 0;

    const float* __restrict__ Wh = dir ? Whb : Whf;
    const float* __restrict__ Wx = dir ? Wxb : Wxf;
    const float* __restrict__ bx = dir ? bxb : bxf;
    const float* __restrict__ bh = dir ? bhb : bhf;

    const int tid = threadIdx.x;
    const int wid = tid >> 6;            // wave id 0..11
    const int kq  = tid / 96;            // k-chunk 0..7 (x-chunk too)
    const int rp  = tid - kq * 96;       // row-pair 0..95
    const int lr0 = 2 * rp;              // local gate-rows lr0, lr0+1
    const int gi  = lr0 >> 6;            // gate 0=r,1=z,2=n
    const int Rg0 = gi * H + w * 64 + (lr0 & 63);   // global gate-row of lr0

    __shared__ float4 h4[SEQ][64];            // full h per sequence (4 KB)
    __shared__ float  P [8][SEQ][194];        // h-dot partials [kq][s][row]
    __shared__ float  Px[8][SEQ][194];        // x-dot partials [kq][s][row]
    __shared__ float4 xb4[2][SEQ][8];         // x_t ping-pong
    __shared__ int    bbS[SEQ], lsS[SEQ];
    __shared__ int    cntL[4];                // monotonic slice-arrival counters

    if (tid < SEQ) { bbS[tid] = plan[g * 4 + tid]; lsS[tid] = slen[g * 4 + tid]; }
    if (tid < 4) cntL[tid] = 0;
    {   // zero h
        float2* hp = (float2*)h4;
        if (tid < 512) hp[tid] = make_float2(0.0f, 0.0f);
    }
    const int L = glen[g];

    // one-time weight load, slice-relative order: wh[q*4+{0,1}] = row Rg0,
    // wh[q*4+{2,3}] = row Rg0+1, covering k = p*64 + kq*8 .. +7, p=(w+q)&3.
    float4 wh[16];
    #pragma unroll
    for (int q = 0; q < 4; ++q) {
        const int p = (w + q) & 3;
        const float* r0 = Wh + (size_t)Rg0 * 256 + p * 64 + kq * 8;
        wh[q * 4 + 0] = ((const float4*)r0)[0];
        wh[q * 4 + 1] = ((const float4*)r0)[1];
        const float* r1 = r0 + 256;
        wh[q * 4 + 2] = ((const float4*)r1)[0];
        wh[q * 4 + 3] = ((const float4*)r1)[1];
    }
    const float4 wx0 = *(const float4*)(Wx + Rg0 * 32 + kq * 4);
    const float4 wx1 = *(const float4*)(Wx + (Rg0 + 1) * 32 + kq * 4);

    // biases for gate threads (tid<256) in registers
    float bxr = 0, bxz = 0, bxn = 0, bhr = 0, bhz = 0, bhn = 0;
    if (tid < 256) {
        const int j2 = tid & 63;
        bxr = bx[w * 64 + j2]; bxz = bx[H + w * 64 + j2]; bxn = bx[2 * H + w * 64 + j2];
        bhr = bh[w * 64 + j2]; bhz = bh[H + w * 64 + j2]; bhn = bh[2 * H + w * 64 + j2];
    }
    __syncthreads();
    // x for step 1 (buffer 1)
    if (tid < 128) {
        const int s = tid >> 5, i = tid & 31;
        const int t0 = dir ? (T - 1) : 0;
        ((float*)xb4)[128 + s * 32 + i] = traj[(bbS[s] * T + t0) * IN + i];
    }
    __syncthreads();

    for (int step = 1; step <= L; ++step) {
        const int buf = step & 1;
        unsigned long long* __restrict__ slabP =
            hgt + (((step - 1) & 1) * NG + g) * (GW * SEQ * 64);   // read h[step-1]
        unsigned long long* __restrict__ slabC =
            hgt + (buf * NG + g) * (GW * SEQ * 64);                // publish h[step]

        // ---- gather: waves 8-10, one peer slice each ----
        if (wid >= 8 && wid < 11) {
            const int pi   = wid - 8;
            const int pw   = (w + 1 + pi) & 3;
            const int lane = tid & 63;
            unsigned long long* sp = slabP + pw * 256 + lane;
            const int tg = step - 1;
            unsigned long long v0 = 0, v1 = 0, v2 = 0, v3 = 0;
            bool d0 = false, d1 = false, d2 = false, d3 = false;
            do {   // 4 loads in flight per lane -> one LLC round trip
                if (!d0) { v0 = __hip_atomic_load(sp,       __ATOMIC_RELAXED,
                               __HIP_MEMORY_SCOPE_AGENT); d0 = ((int)(v0 >> 32) >= tg); }
                if (!d1) { v1 = __hip_atomic_load(sp + 64,  __ATOMIC_RELAXED,
                               __HIP_MEMORY_SCOPE_AGENT); d1 = ((int)(v1 >> 32) >= tg); }
                if (!d2) { v2 = __hip_atomic_load(sp + 128, __ATOMIC_RELAXED,
                               __HIP_MEMORY_SCOPE_AGENT); d2 = ((int)(v2 >> 32) >= tg); }
                if (!d3) { v3 = __hip_atomic_load(sp + 192, __ATOMIC_RELAXED,
                               __HIP_MEMORY_SCOPE_AGENT); d3 = ((int)(v3 >> 32) >= tg); }
            } while (!(d0 && d1 && d2 && d3));
            float* hb = (float*)h4;
            union { unsigned ui; float f; } e;
            e.ui = (unsigned)v0; hb[0 * 256 + pw * 64 + lane] = e.f;
            e.ui = (unsigned)v1; hb[1 * 256 + pw * 64 + lane] = e.f;
            e.ui = (unsigned)v2; hb[2 * 256 + pw * 64 + lane] = e.f;
            e.ui = (unsigned)v3; hb[3 * 256 + pw * 64 + lane] = e.f;
            if (lane == 0)   // release orders the wave's ds_writes before the add
                __hip_atomic_fetch_add(&cntL[pw], 1, __ATOMIC_RELEASE,
                                       __HIP_MEMORY_SCOPE_WORKGROUP);
        }

        // ---- x prefetch for step+1 (wave 11; clean vmcnt path elsewhere) ----
        float2 xv = make_float2(0.0f, 0.0f);
        int xs = 0, xi = 0;
        const bool do_x = (wid == 11) && (step < L);
        if (do_x) {
            const int lane = tid & 63;
            xs = lane >> 4; xi = lane & 15;
            const int tn = dir ? (T - 1 - step) : step;
            xv = ((const float2*)(traj + (size_t)(bbS[xs] * T + tn) * IN))[xi];
        }

        // ---- phase 1: sub-phased partial dots (weights in VGPRs) ----
        float4 a0 = {0,0,0,0}, a1 = {0,0,0,0}, a2 = {0,0,0,0}, a3 = {0,0,0,0};
        float4 c0 = {0,0,0,0}, c1 = {0,0,0,0}, c2 = {0,0,0,0}, c3 = {0,0,0,0};

        // x partials first (x is ready; gives the exchange more slack)
        {
            float4 xq; float2 pv;
            xq = xb4[buf][0][kq];
            pv.x = wx0.x * xq.x + wx0.y * xq.y + wx0.z * xq.z + wx0.w * xq.w;
            pv.y = wx1.x * xq.x + wx1.y * xq.y + wx1.z * xq.z + wx1.w * xq.w;
            *(float2*)&Px[kq][0][lr0] = pv;
            xq = xb4[buf][1][kq];
            pv.x = wx0.x * xq.x + wx0.y * xq.y + wx0.z * xq.z + wx0.w * xq.w;
            pv.y = wx1.x * xq.x + wx1.y * xq.y + wx1.z * xq.z + wx1.w * xq.w;
            *(float2*)&Px[kq][1][lr0] = pv;
            xq = xb4[buf][2][kq];
            pv.x = wx0.x * xq.x + wx0.y * xq.y + wx0.z * xq.z + wx0.w * xq.w;
            pv.y = wx1.x * xq.x + wx1.y * xq.y + wx1.z * xq.z + wx1.w * xq.w;
            *(float2*)&Px[kq][2][lr0] = pv;
            xq = xb4[buf][3][kq];
            pv.x = wx0.x * xq.x + wx0.y * xq.y + wx0.z * xq.z + wx0.w * xq.w;
            pv.y = wx1.x * xq.x + wx1.y * xq.y + wx1.z * xq.z + wx1.w * xq.w;
            *(float2*)&Px[kq][3][lr0] = pv;
        }

        #pragma unroll
        for (int q = 0; q < 4; ++q) {
            const int p = (w + q) & 3;       // q=0 -> own slice, no wait
            if (q) {
                while (__hip_atomic_load(&cntL[p], __ATOMIC_ACQUIRE,
                                         __HIP_MEMORY_SCOPE_WORKGROUP) < step)
                    __builtin_amdgcn_s_sleep(1);
            }
            const int hb = p * 16 + kq * 2;  // float4 index of this slice's 8 k
            float4 hv0, hv1;
            hv0 = h4[0][hb]; hv1 = h4[0][hb + 1];
            FMA4(a0, wh[q * 4 + 0], hv0); FMA4(a0, wh[q * 4 + 1], hv1);
            FMA4(c0, wh[q * 4 + 2], hv0); FMA4(c0, wh[q * 4 + 3], hv1);
            hv0 = h4[1][hb]; hv1 = h4[1][hb + 1];
            FMA4(a1, wh[q * 4 + 0], hv0); FMA4(a1, wh[q * 4 + 1], hv1);
            FMA4(c1, wh[q * 4 + 2], hv0); FMA4(c1, wh[q * 4 + 3], hv1);
            hv0 = h4[2][hb]; hv1 = h4[2][hb + 1];
            FMA4(a2, wh[q * 4 + 0], hv0); FMA4(a2, wh[q * 4 + 1], hv1);
            FMA4(c2, wh[q * 4 + 2], hv0); FMA4(c2, wh[q * 4 + 3], hv1);
            hv0 = h4[3][hb]; hv1 = h4[3][hb + 1];
            FMA4(a3, wh[q * 4 + 0], hv0); FMA4(a3, wh[q * 4 + 1], hv1);
            FMA4(c3, wh[q * 4 + 2], hv0); FMA4(c3, wh[q * 4 + 3], hv1);
        }
        // horizontal sums -> P
        {
            float2 pv;
            pv.x = a0.x + a0.y + a0.z + a0.w; pv.y = c0.x + c0.y + c0.z + c0.w;
            *(float2*)&P[kq][0][lr0] = pv;
            pv.x = a1.x + a1.y + a1.z + a1.w; pv.y = c1.x + c1.y + c1.z + c1.w;
            *(float2*)&P[kq][1][lr0] = pv;
            pv.x = a2.x + a2.y + a2.z + a2.w; pv.y = c2.x + c2.y + c2.z + c2.w;
            *(float2*)&P[kq][2][lr0] = pv;
            pv.x = a3.x + a3.y + a3.z + a3.w; pv.y = c3.x + c3.y + c3.z + c3.w;
            *(float2*)&P[kq][3][lr0] = pv;
        }
        __syncthreads();

        // ---- phase 2: gates + publish (tid<256); wave 11 stores x ----
        if (tid < 256) {
            const int j2 = tid & 63, s = tid >> 6;   // one s per wave
            float hr = 0.f, hz = 0.f, hn_ = 0.f, xr = 0.f, xz = 0.f, xn = 0.f;
            #pragma unroll
            for (int kk = 0; kk < 8; ++kk) {
                hr  += P [kk][s][j2];
                hz  += P [kk][s][64 + j2];
                hn_ += P [kk][s][128 + j2];
                xr  += Px[kk][s][j2];
                xz  += Px[kk][s][64 + j2];
                xn  += Px[kk][s][128 + j2];
            }
            const float r = sigmoidf_(xr + bxr + hr + bhr);
            const float z = sigmoidf_(xz + bxz + hz + bhz);
            const float n = tanhf(xn + bxn + r * (hn_ + bhn));
            const int jg = w * 64 + j2;
            const float hp = ((const float*)h4)[s * 256 + jg];
            const float hnew = (1.0f - z) * n + z * hp;
            ((float*)h4)[s * 256 + jg] = hnew;
            union { float f; unsigned ui; } cv; cv.f = hnew;
            const unsigned long long pk =
                ((unsigned long long)(unsigned)step << 32) | cv.ui;
            __hip_atomic_store(&slabC[w * 256 + s * 64 + j2], pk,
                               __ATOMIC_RELAXED, __HIP_MEMORY_SCOPE_AGENT);
            if (step == lsS[s]) ze[bbS[s] * D + dir * H + jg] = hnew;
        } else if (do_x) {
            ((float2*)xb4)[(buf ^ 1) * 64 + xs * 16 + xi] = xv;
        }
        __syncthreads();
    }
}

// ---------------------------------------------------------------------------
// VQ: fp64 distance accumulation to match the numpy (fp64) argmin ordering.
// ---------------------------------------------------------------------------

__global__ __launch_bounds__(256) void k_vq(
    const float* __restrict__ ze, const float* __restrict__ cbT,
    const float* __restrict__ cb, const double* __restrict__ cbn2,
    int* __restrict__ counts, double* __restrict__ lsum,
    float* __restrict__ out)
{
    __shared__ float lz[D];
    __shared__ double ds[256];
    __shared__ int cs[256];

    const int b = blockIdx.x;
    const int t = threadIdx.x;

    lz[t]       = ze[b * D + t];
    lz[t + 256] = ze[b * D + 256 + t];
    __syncthreads();

    double best = 1e300;
    int bc = 0;
    for (int m = 0; m < NC / 256; ++m) {
        const int c = m * 256 + t;
        double s2 = 0.0;
        #pragma unroll 4
        for (int k = 0; k < D; ++k)
            s2 += (double)lz[k] * (double)cbT[k * NC + c];
        const double dist = cbn2[c] - 2.0 * s2;
        if (dist < best) { best = dist; bc = c; }
    }
    ds[t] = best; cs[t] = bc;
    __syncthreads();
    for (int s = 128; s > 0; s >>= 1) {
        if (t < s) {
            if (ds[t + s] < ds[t] || (ds[t + s] == ds[t] && cs[t + s] < cs[t])) {
                ds[t] = ds[t + s]; cs[t] = cs[t + s];
            }
        }
        __syncthreads();
    }
    const int idx = cs[0];
    __syncthreads();

    if (t == 0) atomicAdd(&counts[idx], 1);

    double loc = 0.0;
    for (int jj = t; jj < D; jj += 256) {
        const float zev = lz[jj];
        const float zqv = cb[idx * D + jj];
        out[b * D + jj] = zev + (zqv - zev);
        const double df = (double)zqv - (double)zev;
        loc += df * df;
    }
    ds[t] = loc;
    __syncthreads();
    for (int s = 128; s > 0; s >>= 1) {
        if (t < s) ds[t] += ds[t + s];
        __syncthreads();
    }
    if (t == 0) atomicAdd(lsum, ds[0]);
}

__global__ void k_final(const int* __restrict__ counts,
                        const double* __restrict__ lsum,
                        float* __restrict__ out)
{
    __shared__ double ds[256];
    const int t = threadIdx.x;
    double s = 0.0;
    for (int c = t; c < NC; c += 256) {
        const double p = (double)counts[c] / (double)B;
        s += p * log(p + 1e-10);
    }
    ds[t] = s;
    __syncthreads();
    for (int r = 128; r > 0; r >>= 1) {
        if (t < r) ds[t] += ds[t + r];
        __syncthreads();
    }
    if (t == 0) {
        out[B * D]     = (float)(lsum[0] * 1.25 / (double)(B * D));
        out[B * D + 1] = (float)exp(-ds[0]);
    }
}

// ---------------------------------------------------------------------------
// launch
// ---------------------------------------------------------------------------

extern "C" void kernel_launch(void* const* d_in, const int* in_sizes, int n_in,
                              void* d_out, int out_size, void* d_ws, size_t ws_size,
                              hipStream_t stream) {
    const float* traj = (const float*)d_in[0];
    const int*   mask = (const int*)d_in[1];
    const float* Wxf  = (const float*)d_in[2];
    const float* Whf  = (const float*)d_in[3];
    const float* bxf  = (const float*)d_in[4];
    const float* bhf  = (const float*)d_in[5];
    const float* Wxb  = (const float*)d_in[6];
    const float* Whb  = (const float*)d_in[7];
    const float* bxb  = (const float*)d_in[8];
    const float* bhb  = (const float*)d_in[9];
    const float* cb   = (const float*)d_in[10];
    float* out = (float*)d_out;

    // workspace layout
    float* ws    = (float*)d_ws;
    float* cbT   = ws;                     // 512*1024 = 524288 floats
    float* zebuf = cbT + 524288;           // 128*512  = 65536
    unsigned long long* hgt =
        (unsigned long long*)(zebuf + 65536);   // 2*64*4*256 u64 = 131072 (1 MB)
    int*   last  = (int*)(hgt + 131072);   // 128
    int*   plan  = last + 128;             // 256
    int*   slen  = plan + 256;             // 256
    int*   glen  = slen + 256;             // 64
    int*   cnts  = glen + 64;              // 1024
    double* cbn2 = (double*)(cnts + 1024 + 4); // 1024 doubles (8B aligned)
    double* lsum = cbn2 + 1024;            // 1 double

    k_zero<<<dim3(512), dim3(256), 0, stream>>>(cnts, lsum, hgt);
    k_lengths<<<dim3(B), dim3(64), 0, stream>>>(mask, last);
    k_plan<<<dim3(1), dim3(B), 0, stream>>>(last, plan, slen, glen);

    k_transpose<<<dim3(2048), dim3(256), 0, stream>>>(cbT, cb, NC, D);
    k_cbn2<<<dim3(4), dim3(256), 0, stream>>>(cb, cbn2);

    k_gru<<<dim3(NG * GW), dim3(NTHR), 0, stream>>>(
        traj, Whf, Whb, Wxf, Wxb, bxf, bhf, bxb, bhb,
        plan, slen, glen, hgt, zebuf);

    k_vq<<<dim3(B), dim3(256), 0, stream>>>(zebuf, cbT, cb, cbn2, cnts, lsum, out);
    k_final<<<dim3(1), dim3(256), 0, stream>>>(cnts, lsum, out);
}